// Round 1
// baseline (20857.440 us; speedup 1.0000x reference)
//
#include <hip/hip_runtime.h>
#include <hip/hip_bf16.h>

// ESN: SEQ=512, B=32, IN=128, H=2048, OUT=128, L=3, LEAK=0.95, washout=32
// Round 1: stream-serialized bf16-MFMA baseline.
// ws layout (u16 elems): packedW0[E0] packedW1[E1] packedW2[E1] packedWout[EP] hbuf[2][3][32*2048]
// ws bytes needed ~= 44.9 MB.

typedef unsigned short u16;
typedef __attribute__((ext_vector_type(8))) __bf16 bf16x8;
typedef __attribute__((ext_vector_type(4))) float f32x4;

#define MFMA16(a,b,c) __builtin_amdgcn_mfma_f32_16x16x32_bf16((a),(b),(c),0,0,0)

#define E0 4456448   // 2048*2176
#define E1 8388608   // 2048*4096
#define EP 786432    // 128*6144

__device__ __forceinline__ float b2f(u16 u){ return __uint_as_float(((unsigned)u)<<16); }
__device__ __forceinline__ u16 f2b(float f){ unsigned x=__float_as_uint(f); return (u16)((x + 0x7FFFu + ((x>>16)&1u))>>16); }

// ---------------- weight pack: fp32 -> bf16 in MFMA B-fragment order ----------------
// For mfma_f32_16x16x32_bf16, B-frag: lane l holds B[k = (l>>4)*8 + e][col = l&15].
// Packed element index for W[j][k] (B = W^T):
//   jt=j>>4, jl=j&15, c=k>>5, ko=k&31, lane=(ko>>3)*16+jl, e=ko&7
//   dst = ((jt*KC + c)*64 + lane)*8 + e     (KC = K/32; each fragment = 1KB contiguous)
__global__ __launch_bounds__(256) void k_pack(const float* __restrict__ wih0, const float* __restrict__ whh0,
    const float* __restrict__ wih1, const float* __restrict__ whh1,
    const float* __restrict__ wih2, const float* __restrict__ whh2,
    const float* __restrict__ wout,
    u16* __restrict__ p0, u16* __restrict__ p1, u16* __restrict__ p2, u16* __restrict__ po)
{
  const long total = (long)E0 + 2L*E1 + EP;
  for (long id = (long)blockIdx.x*blockDim.x + threadIdx.x; id < total; id += (long)gridDim.x*blockDim.x){
    long r = id; int K, j, k; float v; u16* dst;
    if (r < E0){ K=2176; j=(int)(r/2176); k=(int)(r%2176);
      v = (k<128) ? wih0[(size_t)j*128 + k] : whh0[(size_t)j*2048 + (k-128)]; dst=p0; }
    else if ((r -= E0) < E1){ K=4096; j=(int)(r/4096); k=(int)(r%4096);
      v = (k<2048) ? wih1[(size_t)j*2048 + k] : whh1[(size_t)j*2048 + (k-2048)]; dst=p1; }
    else if ((r -= E1) < E1){ K=4096; j=(int)(r/4096); k=(int)(r%4096);
      v = (k<2048) ? wih2[(size_t)j*2048 + k] : whh2[(size_t)j*2048 + (k-2048)]; dst=p2; }
    else { r -= E1; K=6144; j=(int)(r/6144); k=(int)(r%6144); v = wout[(size_t)j*6144 + k]; dst=po; }
    int KC=K>>5, jt=j>>4, jl=j&15, c=k>>5, ko=k&31, lane=((ko>>3)<<4)|jl, e=ko&7;
    dst[(((size_t)jt*KC + c)*64 + lane)*8 + e] = f2b(v);
  }
}

// ---------------- generic hidden-layer update (layers 1,2): K = 4096 ----------------
// X = [xa (k<2048) | xb (k>=2048)], h_old = xb, output -> hout. 128 blocks x 16 cols.
__global__ __launch_bounds__(256) void k_layer(const u16* __restrict__ pW, const float* __restrict__ bias,
    const u16* __restrict__ xa, const u16* __restrict__ xb, u16* __restrict__ hout)
{
  __shared__ float red[4][2][256];
  const int tid=threadIdx.x, wv=tid>>6, ln=tid&63, rr=ln&15, kg=ln>>4;
  const int jt=blockIdx.x;
  f32x4 acc0={0.f,0.f,0.f,0.f}, acc1={0.f,0.f,0.f,0.f};
  const u16* wp = pW + (((size_t)jt*128 + wv*32)*64 + ln)*8;
  int kb = wv*1024 + kg*8;
  #pragma unroll 4
  for (int c=0;c<32;c++){
    bf16x8 bf = *(const bf16x8*)wp; wp += 512;
    const u16* ap = (kb < 2048) ? (xa + kb) : (xb + (kb-2048));
    bf16x8 a0 = *(const bf16x8*)(ap + (size_t)rr*2048);
    bf16x8 a1 = *(const bf16x8*)(ap + (size_t)(16+rr)*2048);
    acc0 = MFMA16(a0,bf,acc0);
    acc1 = MFMA16(a1,bf,acc1);
    kb += 32;
  }
  #pragma unroll
  for (int i=0;i<4;i++){ red[wv][0][(ln<<2)+i]=acc0[i]; red[wv][1][(ln<<2)+i]=acc1[i]; }
  __syncthreads();
  #pragma unroll
  for (int mt=0;mt<2;mt++){
    float v = red[0][mt][tid]+red[1][mt][tid]+red[2][mt][tid]+red[3][mt][tid];
    int l=tid>>2, i=tid&3, row=((l>>4)<<2)+i, col=l&15;
    int b=(mt<<4)+row, j=(jt<<4)+col;
    float pre = v + bias[j];
    float ho = b2f(xb[(size_t)b*2048 + j]);
    float hn = 0.05f*ho + 0.95f*tanhf(pre);
    hout[(size_t)b*2048 + j] = f2b(hn);
  }
}

// ---------------- output projection for step tp (one 16-col tile per call) ----------------
__device__ __forceinline__ void proj_body(float red[4][2][256],
    const u16* __restrict__ pWo, const float* __restrict__ bo,
    const u16* __restrict__ hp0, const u16* __restrict__ hp1, const u16* __restrict__ hp2,
    float* __restrict__ out, const int* __restrict__ washp, int tp, int jt)
{
  const int tid=threadIdx.x, wv=tid>>6, ln=tid&63, rr=ln&15, kg=ln>>4;
  f32x4 acc0={0.f,0.f,0.f,0.f}, acc1={0.f,0.f,0.f,0.f};
  const u16* wp = pWo + (((size_t)jt*192 + wv*48)*64 + ln)*8;
  int kb = wv*1536 + kg*8;
  for (int c=0;c<48;c++){
    bf16x8 bf = *(const bf16x8*)wp; wp += 512;
    int hs = kb>>11, ko = kb&2047;
    const u16* h = (hs==0)?hp0:((hs==1)?hp1:hp2);
    bf16x8 a0 = *(const bf16x8*)(h + (size_t)rr*2048 + ko);
    bf16x8 a1 = *(const bf16x8*)(h + (size_t)(16+rr)*2048 + ko);
    acc0 = MFMA16(a0,bf,acc0);
    acc1 = MFMA16(a1,bf,acc1);
    kb += 32;
  }
  #pragma unroll
  for (int i=0;i<4;i++){ red[wv][0][(ln<<2)+i]=acc0[i]; red[wv][1][(ln<<2)+i]=acc1[i]; }
  __syncthreads();
  const int wash = *washp;
  if (tp < wash) return;
  #pragma unroll
  for (int mt=0;mt<2;mt++){
    float v = red[0][mt][tid]+red[1][mt][tid]+red[2][mt][tid]+red[3][mt][tid];
    int l=tid>>2, i=tid&3, row=((l>>4)<<2)+i, col=l&15;
    int b=(mt<<4)+row, j=(jt<<4)+col;
    out[(((size_t)(tp-wash))*32 + b)*128 + j] = v + bo[j];
  }
}

// ---------------- layer 0 (+ folded projection of step t-1) ----------------
// blocks 0..127: h0 update (K = 128 fp32 input + 2048 h0_prev). blocks 128..135: proj(t-1).
__global__ __launch_bounds__(256) void k_l0proj(const u16* __restrict__ pW0, const float* __restrict__ b0,
    const float* __restrict__ xf, const u16* __restrict__ h0p, u16* __restrict__ h0c,
    const u16* __restrict__ pWo, const float* __restrict__ bo,
    const u16* __restrict__ hp1, const u16* __restrict__ hp2,
    float* __restrict__ out, const int* __restrict__ washp, int t)
{
  __shared__ float red[4][2][256];
  if (blockIdx.x >= 128){
    proj_body(red, pWo, bo, h0p, hp1, hp2, out, washp, t-1, blockIdx.x-128);
    return;
  }
  const int tid=threadIdx.x, wv=tid>>6, ln=tid&63, rr=ln&15, kg=ln>>4;
  const int jt=blockIdx.x;
  f32x4 acc0={0.f,0.f,0.f,0.f}, acc1={0.f,0.f,0.f,0.f};
  const u16* wp = pW0 + (((size_t)jt*68 + wv*17)*64 + ln)*8;
  int kb = wv*544 + kg*8;
  for (int c=0;c<17;c++){
    bf16x8 bf = *(const bf16x8*)wp; wp += 512;
    bf16x8 a0, a1;
    if (kb < 128){
      const float* q0 = xf + rr*128 + kb;
      const float* q1 = xf + (16+rr)*128 + kb;
      #pragma unroll
      for (int e=0;e<8;e++){ a0[e]=(__bf16)q0[e]; a1[e]=(__bf16)q1[e]; }
    } else {
      a0 = *(const bf16x8*)(h0p + (size_t)rr*2048 + (kb-128));
      a1 = *(const bf16x8*)(h0p + (size_t)(16+rr)*2048 + (kb-128));
    }
    acc0 = MFMA16(a0,bf,acc0);
    acc1 = MFMA16(a1,bf,acc1);
    kb += 32;
  }
  #pragma unroll
  for (int i=0;i<4;i++){ red[wv][0][(ln<<2)+i]=acc0[i]; red[wv][1][(ln<<2)+i]=acc1[i]; }
  __syncthreads();
  #pragma unroll
  for (int mt=0;mt<2;mt++){
    float v = red[0][mt][tid]+red[1][mt][tid]+red[2][mt][tid]+red[3][mt][tid];
    int l=tid>>2, i=tid&3, row=((l>>4)<<2)+i, col=l&15;
    int b=(mt<<4)+row, j=(jt<<4)+col;
    float pre = v + b0[j];
    float ho = b2f(h0p[(size_t)b*2048 + j]);
    float hn = 0.05f*ho + 0.95f*tanhf(pre);
    h0c[(size_t)b*2048 + j] = f2b(hn);
  }
}

// ---------------- epilogue: proj(511) + hidden (final h, bf16->fp32) ----------------
__global__ __launch_bounds__(256) void k_epi(const u16* __restrict__ pWo, const float* __restrict__ bo,
    const u16* __restrict__ hp0, const u16* __restrict__ hp1, const u16* __restrict__ hp2,
    float* __restrict__ out, const int* __restrict__ washp)
{
  __shared__ float red[4][2][256];
  if (blockIdx.x < 8){
    proj_body(red, pWo, bo, hp0, hp1, hp2, out, washp, 511, blockIdx.x);
    return;
  }
  const int base = (blockIdx.x-8)*256 + threadIdx.x;
  for (int i = base; i < 196608; i += 24*256){
    int l = i>>16, rem = i&65535;
    const u16* h = (l==0)?hp0:((l==1)?hp1:hp2);
    out[1966080 + i] = b2f(h[rem]);
  }
}

extern "C" void kernel_launch(void* const* d_in, const int* in_sizes, int n_in,
                              void* d_out, int out_size, void* d_ws, size_t ws_size,
                              hipStream_t stream)
{
  (void)in_sizes; (void)n_in; (void)out_size; (void)ws_size;
  const float* input=(const float*)d_in[0];
  const float* wih0=(const float*)d_in[1]; const float* bih0=(const float*)d_in[2];
  const float* whh0=(const float*)d_in[3];
  const float* wih1=(const float*)d_in[4]; const float* bih1=(const float*)d_in[5];
  const float* whh1=(const float*)d_in[6];
  const float* wih2=(const float*)d_in[7]; const float* bih2=(const float*)d_in[8];
  const float* whh2=(const float*)d_in[9];
  const float* wout=(const float*)d_in[10]; const float* bout=(const float*)d_in[11];
  const int* washp=(const int*)d_in[12];
  float* out=(float*)d_out;

  u16* p0=(u16*)d_ws;
  u16* p1=p0+E0;
  u16* p2=p1+E1;
  u16* po=p2+E1;
  u16* hb=po+EP;   // hb[slot(2)][layer(3)][65536]

  k_pack<<<dim3(2048),dim3(256),0,stream>>>(wih0,whh0,wih1,whh1,wih2,whh2,wout,p0,p1,p2,po);
  hipMemsetAsync(hb, 0, (size_t)2*3*65536*sizeof(u16), stream);

  for (int t=0;t<512;t++){
    const int cur=t&1, prv=cur^1;
    u16* h0p=hb+((size_t)prv*3+0)*65536; u16* h0c=hb+((size_t)cur*3+0)*65536;
    u16* h1p=hb+((size_t)prv*3+1)*65536; u16* h1c=hb+((size_t)cur*3+1)*65536;
    u16* h2p=hb+((size_t)prv*3+2)*65536; u16* h2c=hb+((size_t)cur*3+2)*65536;
    k_l0proj<<<dim3(136),dim3(256),0,stream>>>(p0,bih0,input+(size_t)t*4096,h0p,h0c,po,bout,h1p,h2p,out,washp,t);
    k_layer <<<dim3(128),dim3(256),0,stream>>>(p1,bih1,h0c,h1p,h1c);
    k_layer <<<dim3(128),dim3(256),0,stream>>>(p2,bih2,h1c,h2p,h2c);
  }
  u16* f0=hb+((size_t)3+0)*65536; u16* f1=hb+((size_t)3+1)*65536; u16* f2=hb+((size_t)3+2)*65536;
  k_epi<<<dim3(32),dim3(256),0,stream>>>(po,bout,f0,f1,f2,out,washp);
}

// Round 2
// 20819.844 us; speedup vs baseline: 1.0018x; 1.0018x over previous
//
#include <hip/hip_runtime.h>
#include <hip/hip_bf16.h>

// ESN persistent pipelined kernel. Groups: L0=64 blk, L1=64, L2=64, proj=8 (grid 200x256).
// ws: packedW (44 MB) + h slots [3][8][32*2048] bf16 (3 MB) + flags.

typedef unsigned short u16;
typedef __attribute__((ext_vector_type(8))) __bf16 bf16x8;
typedef __attribute__((ext_vector_type(4))) float f32x4;

#define MFMA16(a,b,c) __builtin_amdgcn_mfma_f32_16x16x32_bf16((a),(b),(c),0,0,0)

#define E0 4456448   // 2048*2176
#define E1 8388608   // 2048*4096
#define EP 786432    // 128*6144
#define HSLOT 65536  // 32*2048
#define NSLOT 8

static __device__ __forceinline__ float b2f(u16 u){ return __uint_as_float(((unsigned)u)<<16); }
static __device__ __forceinline__ u16 f2b(float f){ unsigned x=__float_as_uint(f); return (u16)((x + 0x7FFFu + ((x>>16)&1u))>>16); }

// ---------------- weight pack: fp32 -> bf16 in MFMA B-fragment order ----------------
__global__ __launch_bounds__(256) void k_pack(const float* __restrict__ wih0, const float* __restrict__ whh0,
    const float* __restrict__ wih1, const float* __restrict__ whh1,
    const float* __restrict__ wih2, const float* __restrict__ whh2,
    const float* __restrict__ wout,
    u16* __restrict__ p0, u16* __restrict__ p1, u16* __restrict__ p2, u16* __restrict__ po)
{
  const long total = (long)E0 + 2L*E1 + EP;
  for (long id = (long)blockIdx.x*blockDim.x + threadIdx.x; id < total; id += (long)gridDim.x*blockDim.x){
    long r = id; int K, j, k; float v; u16* dst;
    if (r < E0){ K=2176; j=(int)(r/2176); k=(int)(r%2176);
      v = (k<128) ? wih0[(size_t)j*128 + k] : whh0[(size_t)j*2048 + (k-128)]; dst=p0; }
    else if ((r -= E0) < E1){ K=4096; j=(int)(r/4096); k=(int)(r%4096);
      v = (k<2048) ? wih1[(size_t)j*2048 + k] : whh1[(size_t)j*2048 + (k-2048)]; dst=p1; }
    else if ((r -= E1) < E1){ K=4096; j=(int)(r/4096); k=(int)(r%4096);
      v = (k<2048) ? wih2[(size_t)j*2048 + k] : whh2[(size_t)j*2048 + (k-2048)]; dst=p2; }
    else { r -= E1; K=6144; j=(int)(r/6144); k=(int)(r%6144); v = wout[(size_t)j*6144 + k]; dst=po; }
    int KC=K>>5, jt=j>>4, jl=j&15, c=k>>5, ko=k&31, lane=((ko>>3)<<4)|jl, e=ko&7;
    dst[(((size_t)jt*KC + c)*64 + lane)*8 + e] = f2b(v);
  }
}

// ---------------- sync primitives (device-scope, cross-XCD safe) ----------------
static __device__ __forceinline__ void spinwait(unsigned* f, unsigned tgt){
  while (__hip_atomic_load(f, __ATOMIC_ACQUIRE, __HIP_MEMORY_SCOPE_AGENT) < tgt)
    __builtin_amdgcn_s_sleep(2);
}
static __device__ __forceinline__ void post(unsigned* f){
  __hip_atomic_fetch_add(f, 1u, __ATOMIC_RELEASE, __HIP_MEMORY_SCOPE_AGENT);
}

// ---------------- per-tile compute bodies ----------------
// layer 1/2 tile: K = 4096 = [xa | xb], h_old = xb
static __device__ __forceinline__ void tile_layer(const u16* __restrict__ pW, const float* __restrict__ bias,
    const u16* __restrict__ xa, const u16* __restrict__ xb, u16* __restrict__ hout,
    int jt, float (*red)[2][256])
{
  const int tid=threadIdx.x, wv=tid>>6, ln=tid&63, rr=ln&15, kg=ln>>4;
  f32x4 acc0={0.f,0.f,0.f,0.f}, acc1={0.f,0.f,0.f,0.f};
  const u16* wp = pW + (((size_t)jt*128 + wv*32)*64 + ln)*8;
  int kb = wv*1024 + kg*8;
  #pragma unroll 4
  for (int c=0;c<32;c++){
    bf16x8 bf = *(const bf16x8*)wp; wp += 512;
    const u16* ap = (kb < 2048) ? (xa + kb) : (xb + (kb-2048));
    bf16x8 a0 = *(const bf16x8*)(ap + (size_t)rr*2048);
    bf16x8 a1 = *(const bf16x8*)(ap + (size_t)(16+rr)*2048);
    acc0 = MFMA16(a0,bf,acc0);
    acc1 = MFMA16(a1,bf,acc1);
    kb += 32;
  }
  #pragma unroll
  for (int i=0;i<4;i++){ red[wv][0][(ln<<2)+i]=acc0[i]; red[wv][1][(ln<<2)+i]=acc1[i]; }
  __syncthreads();
  #pragma unroll
  for (int mt=0;mt<2;mt++){
    float v = red[0][mt][tid]+red[1][mt][tid]+red[2][mt][tid]+red[3][mt][tid];
    int l=tid>>2, i=tid&3, row=((l>>4)<<2)+i, col=l&15;
    int b=(mt<<4)+row, j=(jt<<4)+col;
    float pre = v + bias[j];
    float hprev = b2f(xb[(size_t)b*2048 + j]);
    hout[(size_t)b*2048 + j] = f2b(0.05f*hprev + 0.95f*tanhf(pre));
  }
}

// layer 0 tile: K = 2176 = [x_t fp32 (128) | h0_prev (2048)]
static __device__ __forceinline__ void tile_l0(const u16* __restrict__ pW, const float* __restrict__ bias,
    const float* __restrict__ xf, const u16* __restrict__ hp, u16* __restrict__ hc,
    int jt, float (*red)[2][256])
{
  const int tid=threadIdx.x, wv=tid>>6, ln=tid&63, rr=ln&15, kg=ln>>4;
  f32x4 acc0={0.f,0.f,0.f,0.f}, acc1={0.f,0.f,0.f,0.f};
  const u16* wp = pW + (((size_t)jt*68 + wv*17)*64 + ln)*8;
  int kb = wv*544 + kg*8;
  for (int c=0;c<17;c++){
    bf16x8 bf = *(const bf16x8*)wp; wp += 512;
    bf16x8 a0, a1;
    if (kb < 128){
      const float* q0 = xf + rr*128 + kb;
      const float* q1 = xf + (16+rr)*128 + kb;
      #pragma unroll
      for (int e=0;e<8;e++){ a0[e]=(__bf16)q0[e]; a1[e]=(__bf16)q1[e]; }
    } else {
      a0 = *(const bf16x8*)(hp + (size_t)rr*2048 + (kb-128));
      a1 = *(const bf16x8*)(hp + (size_t)(16+rr)*2048 + (kb-128));
    }
    acc0 = MFMA16(a0,bf,acc0);
    acc1 = MFMA16(a1,bf,acc1);
    kb += 32;
  }
  #pragma unroll
  for (int i=0;i<4;i++){ red[wv][0][(ln<<2)+i]=acc0[i]; red[wv][1][(ln<<2)+i]=acc1[i]; }
  __syncthreads();
  #pragma unroll
  for (int mt=0;mt<2;mt++){
    float v = red[0][mt][tid]+red[1][mt][tid]+red[2][mt][tid]+red[3][mt][tid];
    int l=tid>>2, i=tid&3, row=((l>>4)<<2)+i, col=l&15;
    int b=(mt<<4)+row, j=(jt<<4)+col;
    float pre = v + bias[j];
    float hprev = b2f(hp[(size_t)b*2048 + j]);
    hc[(size_t)b*2048 + j] = f2b(0.05f*hprev + 0.95f*tanhf(pre));
  }
}

// projection tile: K = 6144 = [h0|h1|h2]
static __device__ __forceinline__ void tile_proj(const u16* __restrict__ pWo, const float* __restrict__ bo,
    const u16* __restrict__ h0, const u16* __restrict__ h1, const u16* __restrict__ h2,
    float* __restrict__ out, int tp, int wash, int jt, float (*red)[2][256])
{
  const int tid=threadIdx.x, wv=tid>>6, ln=tid&63, rr=ln&15, kg=ln>>4;
  f32x4 acc0={0.f,0.f,0.f,0.f}, acc1={0.f,0.f,0.f,0.f};
  const u16* wp = pWo + (((size_t)jt*192 + wv*48)*64 + ln)*8;
  int kb = wv*1536 + kg*8;
  for (int c=0;c<48;c++){
    bf16x8 bf = *(const bf16x8*)wp; wp += 512;
    int hs = kb>>11, ko = kb&2047;
    const u16* h = (hs==0)?h0:((hs==1)?h1:h2);
    bf16x8 a0 = *(const bf16x8*)(h + (size_t)rr*2048 + ko);
    bf16x8 a1 = *(const bf16x8*)(h + (size_t)(16+rr)*2048 + ko);
    acc0 = MFMA16(a0,bf,acc0);
    acc1 = MFMA16(a1,bf,acc1);
    kb += 32;
  }
  #pragma unroll
  for (int i=0;i<4;i++){ red[wv][0][(ln<<2)+i]=acc0[i]; red[wv][1][(ln<<2)+i]=acc1[i]; }
  __syncthreads();
  if (tp < wash) return;
  #pragma unroll
  for (int mt=0;mt<2;mt++){
    float v = red[0][mt][tid]+red[1][mt][tid]+red[2][mt][tid]+red[3][mt][tid];
    int l=tid>>2, i=tid&3, row=((l>>4)<<2)+i, col=l&15;
    int b=(mt<<4)+row, j=(jt<<4)+col;
    out[(((size_t)(tp-wash))*32 + b)*128 + j] = v + bo[j];
  }
}

// ---------------- persistent pipelined kernel ----------------
__global__ __launch_bounds__(256) void k_esn(
    const u16* __restrict__ p0, const u16* __restrict__ p1, const u16* __restrict__ p2, const u16* __restrict__ po,
    const float* __restrict__ b0, const float* __restrict__ b1, const float* __restrict__ b2, const float* __restrict__ bo,
    const float* __restrict__ input, const int* __restrict__ washp,
    u16* hb, unsigned* flags, float* out)
{
  __shared__ float red[4][2][256];
  const int bid = blockIdx.x, tid = threadIdx.x;
  u16* H0 = hb;
  u16* H1 = hb + (size_t)NSLOT*HSLOT;
  u16* H2 = hb + (size_t)2*NSLOT*HSLOT;
  unsigned* F0 = flags; unsigned* F1 = flags+32; unsigned* F2 = flags+64; unsigned* F3 = flags+96;

  if (bid < 64){                                    // ---- layer 0 group ----
    const int jt0 = bid*2, jt1 = jt0+1;
    for (int t=0;t<512;t++){
      if (tid==0){
        spinwait(F0, 64u*t);                        // RAW: own h0(t-1)
        if (t>=NSLOT){ spinwait(F1, 64u*(t-7)); spinwait(F3, 8u*(t-7)); }  // WAR on slot
      }
      __syncthreads();
      const int cur=t&7, prv=(t+7)&7;
      const float* xf = input + (size_t)t*4096;
      const u16* hp = H0 + (size_t)prv*HSLOT;
      u16* hc = H0 + (size_t)cur*HSLOT;
      tile_l0(p0,b0,xf,hp,hc,jt0,red);
      __syncthreads();
      tile_l0(p0,b0,xf,hp,hc,jt1,red);
      __syncthreads();
      if (tid==0) post(F0);
    }
  } else if (bid < 128){                            // ---- layer 1 group ----
    const int r = bid-64, jt0 = r*2, jt1 = jt0+1;
    for (int t=0;t<512;t++){
      if (tid==0){
        spinwait(F0, 64u*(t+1));                    // RAW: h0(t) complete
        spinwait(F1, 64u*t);                        // RAW: own h1(t-1)
        if (t>=NSLOT){ spinwait(F2, 64u*(t-7)); spinwait(F3, 8u*(t-7)); }
      }
      __syncthreads();
      const int cur=t&7, prv=(t+7)&7;
      const u16* xa = H0 + (size_t)cur*HSLOT;
      const u16* xb = H1 + (size_t)prv*HSLOT;
      u16* hc = H1 + (size_t)cur*HSLOT;
      tile_layer(p1,b1,xa,xb,hc,jt0,red);
      __syncthreads();
      tile_layer(p1,b1,xa,xb,hc,jt1,red);
      __syncthreads();
      if (tid==0) post(F1);
    }
  } else if (bid < 192){                            // ---- layer 2 group ----
    const int r = bid-128, jt0 = r*2, jt1 = jt0+1;
    for (int t=0;t<512;t++){
      if (tid==0){
        spinwait(F1, 64u*(t+1));
        spinwait(F2, 64u*t);
        if (t>=NSLOT){ spinwait(F3, 8u*(t-7)); }
      }
      __syncthreads();
      const int cur=t&7, prv=(t+7)&7;
      const u16* xa = H1 + (size_t)cur*HSLOT;
      const u16* xb = H2 + (size_t)prv*HSLOT;
      u16* hc = H2 + (size_t)cur*HSLOT;
      tile_layer(p2,b2,xa,xb,hc,jt0,red);
      __syncthreads();
      tile_layer(p2,b2,xa,xb,hc,jt1,red);
      __syncthreads();
      if (tid==0) post(F2);
    }
  } else {                                          // ---- projection group (8 blocks) ----
    const int jt = bid-192;
    const int wash = *washp;
    for (int t=0;t<512;t++){
      if (tid==0){
        spinwait(F0, 64u*(t+1)); spinwait(F1, 64u*(t+1)); spinwait(F2, 64u*(t+1));
      }
      __syncthreads();
      const int cur=t&7;
      tile_proj(po,bo, H0+(size_t)cur*HSLOT, H1+(size_t)cur*HSLOT, H2+(size_t)cur*HSLOT,
                out, t, wash, jt, red);
      __syncthreads();
      if (tid==0) post(F3);
    }
    // epilogue: final hidden state (slot 511%8 = 7), fp32
    const u16* hs0 = H0 + (size_t)7*HSLOT;
    const u16* hs1 = H1 + (size_t)7*HSLOT;
    const u16* hs2 = H2 + (size_t)7*HSLOT;
    const int gt = jt*256 + tid;                    // 0..2047
    for (int q=gt; q<49152; q+=2048){
      int i = q*4, l = i>>16, rem = i&65535;
      const u16* h = (l==0)?hs0:((l==1)?hs1:hs2);
      f32x4 v = { b2f(h[rem]), b2f(h[rem+1]), b2f(h[rem+2]), b2f(h[rem+3]) };
      *(f32x4*)(out + 1966080 + i) = v;
    }
  }
}

extern "C" void kernel_launch(void* const* d_in, const int* in_sizes, int n_in,
                              void* d_out, int out_size, void* d_ws, size_t ws_size,
                              hipStream_t stream)
{
  (void)in_sizes; (void)n_in; (void)out_size; (void)ws_size;
  const float* input=(const float*)d_in[0];
  const float* wih0=(const float*)d_in[1]; const float* bih0=(const float*)d_in[2];
  const float* whh0=(const float*)d_in[3];
  const float* wih1=(const float*)d_in[4]; const float* bih1=(const float*)d_in[5];
  const float* whh1=(const float*)d_in[6];
  const float* wih2=(const float*)d_in[7]; const float* bih2=(const float*)d_in[8];
  const float* whh2=(const float*)d_in[9];
  const float* wout=(const float*)d_in[10]; const float* bout=(const float*)d_in[11];
  const int* washp=(const int*)d_in[12];
  float* out=(float*)d_out;

  u16* p0=(u16*)d_ws;
  u16* p1=p0+E0;
  u16* p2=p1+E1;
  u16* po=p2+E1;
  u16* hb=po+EP;                                   // 3*8*65536 u16
  unsigned* flags=(unsigned*)(hb + (size_t)3*NSLOT*HSLOT);

  k_pack<<<dim3(2048),dim3(256),0,stream>>>(wih0,whh0,wih1,whh1,wih2,whh2,wout,p0,p1,p2,po);
  hipMemsetAsync(hb, 0, (size_t)3*NSLOT*HSLOT*sizeof(u16) + 128*sizeof(unsigned), stream);

  void* args[] = { (void*)&p0, (void*)&p1, (void*)&p2, (void*)&po,
                   (void*)&bih0, (void*)&bih1, (void*)&bih2, (void*)&bout,
                   (void*)&input, (void*)&washp,
                   (void*)&hb, (void*)&flags, (void*)&out };
  hipLaunchCooperativeKernel((const void*)k_esn, dim3(200), dim3(256), args, 0, stream);
}

// Round 3
// 7722.533 us; speedup vs baseline: 2.7009x; 2.6960x over previous
//
#include <hip/hip_runtime.h>
#include <hip/hip_bf16.h>

// ESN weight-stationary persistent pipeline.
// Groups: L0=64 blk, L1=64, L2=64, proj=8 (grid 200 x 512 threads, 8 waves).
// Weights live in VGPRs (loaded once). Activations passed between stages in
// MFMA A-fragment layout so consumer loads are fully coalesced.

typedef unsigned short u16;
typedef __attribute__((ext_vector_type(8))) __bf16 bf16x8;
typedef __attribute__((ext_vector_type(4))) float f32x4;

#define MFMA16(a,b,c) __builtin_amdgcn_mfma_f32_16x16x32_bf16((a),(b),(c),0,0,0)

#define KC0 72                 // L0 K-chunks (2176 real -> pad to 2304, zeros)
#define KC1 128                // L1/L2 K-chunks (4096)
#define KCP 192                // proj K-chunks (6144)
#define E0P (128*KC0*512)      // packed W0 u16 elems
#define E1P (128*KC1*512)
#define EPP (8*KCP*512)
#define CH 1024                // u16 per A-frag chunk: [half2][lane64][e8]
#define S0 (68*CH)             // H0 slot: 64 chunks + 4 zero-pad chunks
#define S12 (64*CH)
#define NSLOT 8

static __device__ __forceinline__ float b2f(u16 u){ return __uint_as_float(((unsigned)u)<<16); }
static __device__ __forceinline__ u16 f2b(float f){ unsigned x=__float_as_uint(f); return (u16)((x + 0x7FFFu + ((x>>16)&1u))>>16); }
// h element (b,j) -> offset within an A-frag h buffer
static __device__ __forceinline__ int frag_addr(int b, int j){
  int c=j>>5, ko=j&31, half=b>>4, lane=(b&15)|((ko>>3)<<4), e=ko&7;
  return ((c*2+half)*64+lane)*8+e;
}

// relaxed spin (no repeated L2 inval), one acquire on success
static __device__ __forceinline__ void waitflag(unsigned* f, unsigned tgt){
  while (__hip_atomic_load(f, __ATOMIC_RELAXED, __HIP_MEMORY_SCOPE_AGENT) < tgt)
    __builtin_amdgcn_s_sleep(4);
  unsigned v = __hip_atomic_load(f, __ATOMIC_ACQUIRE, __HIP_MEMORY_SCOPE_AGENT);
  asm volatile("" :: "v"(v) : "memory");
}
static __device__ __forceinline__ void post(unsigned* f){
  __hip_atomic_fetch_add(f, 1u, __ATOMIC_RELEASE, __HIP_MEMORY_SCOPE_AGENT);
}

// ---------------- weight pack: fp32 -> bf16 B-fragments (per-matrix KC) ----------------
__global__ __launch_bounds__(256) void k_pack(const float* __restrict__ wih0, const float* __restrict__ whh0,
    const float* __restrict__ wih1, const float* __restrict__ whh1,
    const float* __restrict__ wih2, const float* __restrict__ whh2,
    const float* __restrict__ wout,
    u16* __restrict__ p0, u16* __restrict__ p1, u16* __restrict__ p2, u16* __restrict__ po)
{
  const long SRC0 = 2048L*2176, SRC1 = 2048L*4096, SRCP = 128L*6144;
  const long total = SRC0 + 2*SRC1 + SRCP;
  for (long id = (long)blockIdx.x*blockDim.x + threadIdx.x; id < total; id += (long)gridDim.x*blockDim.x){
    long r = id; int KC, j, k; float v; u16* dst;
    if (r < SRC0){ KC=KC0; j=(int)(r/2176); k=(int)(r%2176);
      v = (k<128) ? wih0[(size_t)j*128 + k] : whh0[(size_t)j*2048 + (k-128)]; dst=p0; }
    else if ((r -= SRC0) < SRC1){ KC=KC1; j=(int)(r/4096); k=(int)(r%4096);
      v = (k<2048) ? wih1[(size_t)j*2048 + k] : whh1[(size_t)j*2048 + (k-2048)]; dst=p1; }
    else if ((r -= SRC1) < SRC1){ KC=KC1; j=(int)(r/4096); k=(int)(r%4096);
      v = (k<2048) ? wih2[(size_t)j*2048 + k] : whh2[(size_t)j*2048 + (k-2048)]; dst=p2; }
    else { r -= SRC1; KC=KCP; j=(int)(r/6144); k=(int)(r%6144); v = wout[(size_t)j*6144 + k]; dst=po; }
    int jt=j>>4, jl=j&15, c=k>>5, ko=k&31, lane=((ko>>3)<<4)|jl, e=ko&7;
    dst[(((size_t)jt*KC + c)*64 + lane)*8 + e] = f2b(v);
  }
}

// ---------------- layer 1/2 persistent loop (weights in regs) ----------------
static __device__ __forceinline__ void run_l12(
    const u16* __restrict__ pW, const float* __restrict__ bias,
    const u16* __restrict__ A0slots, size_t a0stride,   // chunks 0..63 source (cur slot)
    u16* OWN,                                            // own h slots (prv = A1 + leak; cur = write)
    unsigned* Fup, unsigned* Fown, unsigned* FwarA, unsigned warAmul,
    unsigned* FwarB, unsigned warBmul,
    int jt0, float (*red)[2][2][256])
{
  const int tid=threadIdx.x, w=tid>>6, ln=tid&63;
  bf16x8 wreg[2][16];
  #pragma unroll
  for (int u=0;u<2;u++)
    #pragma unroll
    for (int ci=0;ci<16;ci++)
      wreg[u][ci] = *(const bf16x8*)(pW + (((size_t)(jt0+u)*KC1 + (w*16+ci))*64 + ln)*8);

  for (int t=0;t<512;t++){
    if (tid==0){
      waitflag(Fup, 64u*(unsigned)(t+1));
      waitflag(Fown, 64u*(unsigned)t);
      if (t>=NSLOT){
        waitflag(FwarA, warAmul*(unsigned)(t-7));
        if (FwarB) waitflag(FwarB, warBmul*(unsigned)(t-7));
      }
    }
    __syncthreads();
    const int cur=t&7, prv=(t+7)&7;
    const u16* a0base = (w<4) ? A0slots + (size_t)cur*a0stride + (size_t)(w*16)*CH
                              : OWN + (size_t)prv*S12 + (size_t)((w-4)*16)*CH;
    f32x4 acc00={0,0,0,0},acc01={0,0,0,0},acc10={0,0,0,0},acc11={0,0,0,0};
    #pragma unroll
    for (int ci=0;ci<16;ci++){
      const u16* ap = a0base + (size_t)ci*CH;
      bf16x8 a0 = *(const bf16x8*)(ap + ln*8);
      bf16x8 a1 = *(const bf16x8*)(ap + 512 + ln*8);
      acc00 = MFMA16(a0, wreg[0][ci], acc00);
      acc01 = MFMA16(a1, wreg[0][ci], acc01);
      acc10 = MFMA16(a0, wreg[1][ci], acc10);
      acc11 = MFMA16(a1, wreg[1][ci], acc11);
    }
    #pragma unroll
    for (int i=0;i<4;i++){
      red[w][0][0][(ln<<2)+i]=acc00[i]; red[w][0][1][(ln<<2)+i]=acc01[i];
      red[w][1][0][(ln<<2)+i]=acc10[i]; red[w][1][1][(ln<<2)+i]=acc11[i];
    }
    __syncthreads();
    {
      const u16* hprv = OWN + (size_t)prv*S12;
      u16* hcur = OWN + (size_t)cur*S12;
      const int h = tid>>8, pos = tid&255;
      #pragma unroll
      for (int u=0;u<2;u++){
        float v = 0.f;
        #pragma unroll
        for (int ww=0;ww<8;ww++) v += red[ww][u][h][pos];
        int l=pos>>2, i=pos&3, col=l&15, row=((l>>4)<<2)+i;
        int b=(h<<4)+row, j=((jt0+u)<<4)+col;
        float pre = v + bias[j];
        int fa = frag_addr(b,j);
        float hp = b2f(hprv[fa]);
        hcur[fa] = f2b(0.05f*hp + 0.95f*tanhf(pre));
      }
    }
    __syncthreads();
    if (tid==0) post(Fown);
  }
}

// ---------------- layer 0 persistent loop ----------------
static __device__ __forceinline__ void run_l0(
    const u16* __restrict__ pW, const float* __restrict__ bias, const float* __restrict__ input,
    u16* H0, unsigned* F0, unsigned* F1, unsigned* F3,
    int jt0, float (*red)[2][2][256])
{
  const int tid=threadIdx.x, w=tid>>6, ln=tid&63, rr=ln&15, kg=ln>>4;
  bf16x8 wreg[2][9];
  #pragma unroll
  for (int u=0;u<2;u++)
    #pragma unroll
    for (int ci=0;ci<9;ci++)
      wreg[u][ci] = *(const bf16x8*)(pW + (((size_t)(jt0+u)*KC0 + (w*9+ci))*64 + ln)*8);

  for (int t=0;t<512;t++){
    if (tid==0){
      waitflag(F0, 64u*(unsigned)t);
      if (t>=NSLOT){ waitflag(F1, 64u*(unsigned)(t-7)); waitflag(F3, 8u*(unsigned)(t-7)); }
    }
    __syncthreads();
    const int cur=t&7, prv=(t+7)&7;
    const float* xf = input + (size_t)t*4096;
    const u16* h0prv = H0 + (size_t)prv*S0;
    f32x4 acc00={0,0,0,0},acc01={0,0,0,0},acc10={0,0,0,0},acc11={0,0,0,0};
    #pragma unroll
    for (int ci=0;ci<9;ci++){
      bf16x8 a0, a1;
      if (w==0 && ci<4){
        const float* q0 = xf + rr*128 + ci*32 + kg*8;
        const float* q1 = q0 + 16*128;
        f32x4 xa=*(const f32x4*)q0, xb=*(const f32x4*)(q0+4);
        f32x4 ya=*(const f32x4*)q1, yb=*(const f32x4*)(q1+4);
        #pragma unroll
        for (int e=0;e<4;e++){ a0[e]=(__bf16)xa[e]; a0[e+4]=(__bf16)xb[e];
                               a1[e]=(__bf16)ya[e]; a1[e+4]=(__bf16)yb[e]; }
      } else {
        const u16* ap = h0prv + (size_t)(w*9+ci-4)*CH;
        a0 = *(const bf16x8*)(ap + ln*8);
        a1 = *(const bf16x8*)(ap + 512 + ln*8);
      }
      acc00 = MFMA16(a0, wreg[0][ci], acc00);
      acc01 = MFMA16(a1, wreg[0][ci], acc01);
      acc10 = MFMA16(a0, wreg[1][ci], acc10);
      acc11 = MFMA16(a1, wreg[1][ci], acc11);
    }
    #pragma unroll
    for (int i=0;i<4;i++){
      red[w][0][0][(ln<<2)+i]=acc00[i]; red[w][0][1][(ln<<2)+i]=acc01[i];
      red[w][1][0][(ln<<2)+i]=acc10[i]; red[w][1][1][(ln<<2)+i]=acc11[i];
    }
    __syncthreads();
    {
      u16* hcur = H0 + (size_t)cur*S0;
      const int h = tid>>8, pos = tid&255;
      #pragma unroll
      for (int u=0;u<2;u++){
        float v = 0.f;
        #pragma unroll
        for (int ww=0;ww<8;ww++) v += red[ww][u][h][pos];
        int l=pos>>2, i=pos&3, col=l&15, row=((l>>4)<<2)+i;
        int b=(h<<4)+row, j=((jt0+u)<<4)+col;
        float pre = v + bias[j];
        int fa = frag_addr(b,j);
        float hp = b2f(h0prv[fa]);
        hcur[fa] = f2b(0.05f*hp + 0.95f*tanhf(pre));
      }
    }
    __syncthreads();
    if (tid==0) post(F0);
  }
}

// ---------------- projection persistent loop + final-h epilogue ----------------
static __device__ __forceinline__ void run_proj(
    const u16* __restrict__ pW, const float* __restrict__ bo,
    const u16* __restrict__ H0, const u16* __restrict__ H1, const u16* __restrict__ H2,
    float* __restrict__ out, const int* __restrict__ washp,
    unsigned* F0, unsigned* F1, unsigned* F2, unsigned* F3,
    int jt, float (*red)[2][2][256])
{
  const int tid=threadIdx.x, w=tid>>6, ln=tid&63;
  bf16x8 wreg[24];
  #pragma unroll
  for (int ci=0;ci<24;ci++)
    wreg[ci] = *(const bf16x8*)(pW + (((size_t)jt*KCP + (w*24+ci))*64 + ln)*8);
  const int wash = *washp;

  for (int t=0;t<512;t++){
    if (tid==0){
      waitflag(F0, 64u*(unsigned)(t+1));
      waitflag(F1, 64u*(unsigned)(t+1));
      waitflag(F2, 64u*(unsigned)(t+1));
    }
    __syncthreads();
    const int cur=t&7;
    const u16* h0c = H0 + (size_t)cur*S0;
    const u16* h1c = H1 + (size_t)cur*S12;
    const u16* h2c = H2 + (size_t)cur*S12;
    f32x4 acc0={0,0,0,0}, acc1={0,0,0,0};
    #pragma unroll
    for (int ci=0;ci<24;ci++){
      const int kc = w*24+ci;
      const u16* ap = (kc<64) ? h0c + (size_t)kc*CH
                    : (kc<128) ? h1c + (size_t)(kc-64)*CH
                               : h2c + (size_t)(kc-128)*CH;
      bf16x8 a0 = *(const bf16x8*)(ap + ln*8);
      bf16x8 a1 = *(const bf16x8*)(ap + 512 + ln*8);
      acc0 = MFMA16(a0, wreg[ci], acc0);
      acc1 = MFMA16(a1, wreg[ci], acc1);
    }
    #pragma unroll
    for (int i=0;i<4;i++){ red[w][0][0][(ln<<2)+i]=acc0[i]; red[w][0][1][(ln<<2)+i]=acc1[i]; }
    __syncthreads();
    if (t >= wash){
      const int h=tid>>8, pos=tid&255;
      float v=0.f;
      #pragma unroll
      for (int ww=0;ww<8;ww++) v += red[ww][0][h][pos];
      int l=pos>>2, i=pos&3, col=l&15, row=((l>>4)<<2)+i;
      int b=(h<<4)+row, j=(jt<<4)+col;
      out[(((size_t)(t-wash))*32 + b)*128 + j] = v + bo[j];
    }
    __syncthreads();
    if (tid==0) post(F3);
  }
  // final hidden state: slot 7, frag layout -> [layer][b][j] fp32
  for (int q = jt*512 + tid; q < 196608; q += 4096){
    int l = q>>16, rem = q&65535, b = rem>>11, j = rem&2047;
    const u16* h = (l==0)? H0+(size_t)7*S0 : ((l==1)? H1+(size_t)7*S12 : H2+(size_t)7*S12);
    out[1966080 + q] = b2f(h[frag_addr(b,j)]);
  }
}

// ---------------- top-level persistent kernel ----------------
__global__ __launch_bounds__(512) void k_esn(
    const u16* __restrict__ p0, const u16* __restrict__ p1, const u16* __restrict__ p2, const u16* __restrict__ po,
    const float* __restrict__ b0, const float* __restrict__ b1, const float* __restrict__ b2, const float* __restrict__ bo,
    const float* __restrict__ input, const int* __restrict__ washp,
    u16* H0, u16* H1, u16* H2, unsigned* flags, float* out)
{
  __shared__ float red[8][2][2][256];
  const int bid = blockIdx.x;
  unsigned* F0 = flags; unsigned* F1 = flags+32; unsigned* F2 = flags+64; unsigned* F3 = flags+96;

  if (bid < 64)       run_l0 (p0, b0, input, H0, F0, F1, F3, bid*2, red);
  else if (bid < 128) run_l12(p1, b1, H0, S0,  H1, F0, F1, F2, 64u, F3, 8u, (bid-64)*2, red);
  else if (bid < 192) run_l12(p2, b2, H1, S12, H2, F1, F2, F3, 8u, nullptr, 0u, (bid-128)*2, red);
  else                run_proj(po, bo, H0, H1, H2, out, washp, F0, F1, F2, F3, bid-192, red);
}

extern "C" void kernel_launch(void* const* d_in, const int* in_sizes, int n_in,
                              void* d_out, int out_size, void* d_ws, size_t ws_size,
                              hipStream_t stream)
{
  (void)in_sizes; (void)n_in; (void)out_size; (void)ws_size;
  const float* input=(const float*)d_in[0];
  const float* wih0=(const float*)d_in[1]; const float* bih0=(const float*)d_in[2];
  const float* whh0=(const float*)d_in[3];
  const float* wih1=(const float*)d_in[4]; const float* bih1=(const float*)d_in[5];
  const float* whh1=(const float*)d_in[6];
  const float* wih2=(const float*)d_in[7]; const float* bih2=(const float*)d_in[8];
  const float* whh2=(const float*)d_in[9];
  const float* wout=(const float*)d_in[10]; const float* bout=(const float*)d_in[11];
  const int* washp=(const int*)d_in[12];
  float* out=(float*)d_out;

  u16* p0=(u16*)d_ws;
  u16* p1=p0+E0P;
  u16* p2=p1+E1P;
  u16* po=p2+E1P;
  u16* H0=po+EPP;
  u16* H1=H0+(size_t)NSLOT*S0;
  u16* H2=H1+(size_t)NSLOT*S12;
  unsigned* flags=(unsigned*)(H2+(size_t)NSLOT*S12);
  size_t totbytes = ((char*)(flags+128)) - ((char*)d_ws);

  hipMemsetAsync(d_ws, 0, totbytes, stream);
  k_pack<<<dim3(2048),dim3(256),0,stream>>>(wih0,whh0,wih1,whh1,wih2,whh2,wout,p0,p1,p2,po);

  void* args[] = { (void*)&p0, (void*)&p1, (void*)&p2, (void*)&po,
                   (void*)&bih0, (void*)&bih1, (void*)&bih2, (void*)&bout,
                   (void*)&input, (void*)&washp,
                   (void*)&H0, (void*)&H1, (void*)&H2, (void*)&flags, (void*)&out };
  hipLaunchCooperativeKernel((const void*)k_esn, dim3(200), dim3(512), args, 0, stream);
}

// Round 4
// 5706.193 us; speedup vs baseline: 3.6552x; 1.3534x over previous
//
#include <hip/hip_runtime.h>
#include <hip/hip_bf16.h>

// ESN weight-stationary persistent pipeline, fence-free sync.
// Groups: L0=64 blk, L1=64, L2=64, proj=8 (grid 200 x 512 threads).
// Weights in VGPRs. Activations cross blocks via sc0sc1 write-through stores;
// per-block seqno arrays replace atomic flags; one buffer_inv per block/step.

typedef unsigned short u16;
typedef __attribute__((ext_vector_type(8))) __bf16 bf16x8;
typedef __attribute__((ext_vector_type(4))) float f32x4;

#define MFMA16(a,b,c) __builtin_amdgcn_mfma_f32_16x16x32_bf16((a),(b),(c),0,0,0)

#define KC0 72                 // L0 K-chunks (2176 -> pad 2304)
#define KC1 128                // L1/L2 K-chunks (4096)
#define KCP 192                // proj K-chunks (6144)
#define E0P (128*KC0*512)
#define E1P (128*KC1*512)
#define EPP (8*KCP*512)
#define CH 1024                // u16 per chunk: [half2][lane64][e8]
#define S0 (68*CH)             // H0 slot: 64 chunks + 4 zero-pad
#define S12 (64*CH)
#define NSLOT 8

static __device__ __forceinline__ float b2f(u16 u){ return __uint_as_float(((unsigned)u)<<16); }
static __device__ __forceinline__ u16 f2b(float f){ unsigned x=__float_as_uint(f); return (u16)((x + 0x7FFFu + ((x>>16)&1u))>>16); }
static __device__ __forceinline__ int frag_addr(int b, int j){
  int c=j>>5, ko=j&31, half=b>>4, lane=(b&15)|((ko>>3)<<4), e=ko&7;
  return ((c*2+half)*64+lane)*8+e;
}

// ---- coherent (cache-bypass) primitives ----
static __device__ __forceinline__ void st_b128_sc(u16* p, f32x4 v){
  asm volatile("global_store_dwordx4 %0, %1, off sc0 sc1" :: "v"(p), "v"(v) : "memory");
}
static __device__ __forceinline__ void st_b32_sc(unsigned* p, unsigned v){
  asm volatile("global_store_dword %0, %1, off sc0 sc1" :: "v"(p), "v"(v) : "memory");
}
static __device__ __forceinline__ void drain(){
  asm volatile("s_waitcnt vmcnt(0)" ::: "memory");
}
static __device__ __forceinline__ void acq_inv(){   // invalidate L2 (+L1) before reading fresh data
  asm volatile("buffer_inv sc1\n\ts_waitcnt vmcnt(0)" ::: "memory");
}
static __device__ __forceinline__ void rel_wb(){    // flush any dirty lines to coherence point
  asm volatile("buffer_wbl2 sc1\n\ts_waitcnt vmcnt(0)" ::: "memory");
}

// wave-parallel seqno poll: wave 0, lane i watches producer i.
static __device__ __forceinline__ void poll4(int lane,
    const unsigned* a, unsigned ta,
    const unsigned* b, unsigned tb,
    const unsigned* c, unsigned tc, int nc,
    const unsigned* d, unsigned td)
{
  for(;;){
    unsigned va=0, vb=0, vc=0, vd=0;
    asm volatile("global_load_dword %0, %1, off sc0 sc1" : "=v"(va) : "v"(a+lane));
    if (b) asm volatile("global_load_dword %0, %1, off sc0 sc1" : "=v"(vb) : "v"(b+lane));
    if (c) asm volatile("global_load_dword %0, %1, off sc0 sc1" : "=v"(vc) : "v"(c+(lane<nc?lane:0)));
    if (d) asm volatile("global_load_dword %0, %1, off sc0 sc1" : "=v"(vd) : "v"(d+(lane<8?lane:0)));
    asm volatile("s_waitcnt vmcnt(0)" ::: "memory");
    __builtin_amdgcn_sched_barrier(0);
    bool ok = (va>=ta);
    if (b) ok &= (vb>=tb);
    if (c) ok &= (lane>=nc) || (vc>=tc);
    if (d) ok &= (lane>=8) || (vd>=td);
    if (__all(ok)) return;
    __builtin_amdgcn_s_sleep(8);
  }
}

// ---------------- weight pack: fp32 -> bf16 B-fragments, 16B stores ----------------
__global__ __launch_bounds__(256) void k_pack(const float* __restrict__ wih0, const float* __restrict__ whh0,
    const float* __restrict__ wih1, const float* __restrict__ whh1,
    const float* __restrict__ wih2, const float* __restrict__ whh2,
    const float* __restrict__ wout,
    u16* __restrict__ p0, u16* __restrict__ p1, u16* __restrict__ p2, u16* __restrict__ po)
{
  const long SRC0 = 2048L*2176, SRC1 = 2048L*4096, SRCP = 128L*6144;
  const long total8 = (SRC0 + 2*SRC1 + SRCP) >> 3;
  for (long id = (long)blockIdx.x*blockDim.x + threadIdx.x; id < total8; id += (long)gridDim.x*blockDim.x){
    long r = id<<3; int KC, j, k; u16* dst;
    const float* sa; const float* sb; int split;
    if (r < SRC0){ KC=KC0; j=(int)(r/2176); k=(int)(r%2176); sa=wih0+(size_t)j*128; sb=whh0+(size_t)j*2048; split=128; dst=p0; }
    else if ((r -= SRC0) < SRC1){ KC=KC1; j=(int)(r/4096); k=(int)(r%4096); sa=wih1+(size_t)j*2048; sb=whh1+(size_t)j*2048; split=2048; dst=p1; }
    else if ((r -= SRC1) < SRC1){ KC=KC1; j=(int)(r/4096); k=(int)(r%4096); sa=wih2+(size_t)j*2048; sb=whh2+(size_t)j*2048; split=2048; dst=p2; }
    else { r -= SRC1; KC=KCP; j=(int)(r/6144); k=(int)(r%6144); sa=wout+(size_t)j*6144; sb=sa; split=6144; dst=po; }
    const float* src = (k<split) ? (sa + k) : (sb + (k - split));
    u16 tmp[8];
    #pragma unroll
    for (int e=0;e<8;e++) tmp[e] = f2b(src[e]);
    int jt=j>>4, jl=j&15, c=k>>5, ko=k&31, lane=((ko>>3)<<4)|jl;
    u16* dp = dst + (((size_t)jt*KC + c)*64 + lane)*8;
    *(f32x4*)dp = *(f32x4*)tmp;
  }
}

// ---------------- layer 1/2 persistent loop ----------------
static __device__ __forceinline__ void run_l12(
    const u16* __restrict__ pW, const float* __restrict__ bias,
    const u16* __restrict__ A0slots, size_t a0stride, u16* OWN,
    unsigned* SEQup, unsigned* SEQown, unsigned* Sc, int nc, unsigned* Sd,
    int jt0, float (*red)[2][2][256], u16* ldsout)
{
  const int tid=threadIdx.x, w=tid>>6, ln=tid&63;
  bf16x8 wreg[2][16];
  #pragma unroll
  for (int u=0;u<2;u++)
    #pragma unroll
    for (int ci=0;ci<16;ci++)
      wreg[u][ci] = *(const bf16x8*)(pW + (((size_t)(jt0+u)*KC1 + (w*16+ci))*64 + ln)*8);

  const int h_=tid>>8, pos=tid&255, l_=pos>>2, i_=pos&3, col_=l_&15, row_=((l_>>4)<<2)+i_, b_=(h_<<4)+row_;
  const float bv0=bias[(jt0<<4)+col_], bv1=bias[((jt0+1)<<4)+col_];
  const int ko0=col_, ko1=16+col_;
  const int faw0=((h_*64)+((b_&15)|((ko0>>3)<<4)))*8+(ko0&7);
  const int faw1=((h_*64)+((b_&15)|((ko1>>3)<<4)))*8+(ko1&7);
  const int myc=jt0>>1, gidx=jt0>>1;

  for (int t=0;t<512;t++){
    if (tid<64){
      poll4(tid, SEQup,(unsigned)(t+1), SEQown,(unsigned)t,
            (t>=NSLOT)?Sc:nullptr,(unsigned)(t-7),nc,
            (t>=NSLOT)?Sd:nullptr,(unsigned)(t-7));
      if (tid==0) acq_inv();
    }
    __syncthreads();
    const int cur=t&7, prv=(t+7)&7;
    const u16* a0base = (w<4) ? A0slots + (size_t)cur*a0stride + (size_t)(w*16)*CH
                              : OWN + (size_t)prv*S12 + (size_t)((w-4)*16)*CH;
    f32x4 acc00={0,0,0,0},acc01={0,0,0,0},acc10={0,0,0,0},acc11={0,0,0,0};
    #pragma unroll
    for (int ci=0;ci<16;ci++){
      const u16* ap = a0base + (size_t)ci*CH;
      bf16x8 a0 = *(const bf16x8*)(ap + ln*8);
      bf16x8 a1 = *(const bf16x8*)(ap + 512 + ln*8);
      acc00 = MFMA16(a0, wreg[0][ci], acc00);
      acc01 = MFMA16(a1, wreg[0][ci], acc01);
      acc10 = MFMA16(a0, wreg[1][ci], acc10);
      acc11 = MFMA16(a1, wreg[1][ci], acc11);
    }
    #pragma unroll
    for (int i=0;i<4;i++){
      red[w][0][0][(ln<<2)+i]=acc00[i]; red[w][0][1][(ln<<2)+i]=acc01[i];
      red[w][1][0][(ln<<2)+i]=acc10[i]; red[w][1][1][(ln<<2)+i]=acc11[i];
    }
    __syncthreads();
    {
      const u16* hprvc = OWN + (size_t)prv*S12 + (size_t)myc*CH;
      float v0=0.f, v1=0.f;
      #pragma unroll
      for (int ww=0;ww<8;ww++){ v0 += red[ww][0][h_][pos]; v1 += red[ww][1][h_][pos]; }
      float hp0 = b2f(hprvc[faw0]);
      float hp1 = b2f(hprvc[faw1]);
      ldsout[faw0] = f2b(0.05f*hp0 + 0.95f*tanhf(v0 + bv0));
      ldsout[faw1] = f2b(0.05f*hp1 + 0.95f*tanhf(v1 + bv1));
    }
    __syncthreads();
    if (tid<128){
      f32x4 vv = *(const f32x4*)(ldsout + tid*8);
      st_b128_sc(OWN + (size_t)cur*S12 + (size_t)myc*CH + tid*8, vv);
    }
    drain();
    __syncthreads();
    if (tid==0){ rel_wb(); st_b32_sc(SEQown+gidx, (unsigned)(t+1)); }
  }
}

// ---------------- layer 0 persistent loop ----------------
static __device__ __forceinline__ void run_l0(
    const u16* __restrict__ pW, const float* __restrict__ bias, const float* __restrict__ input,
    u16* H0, unsigned* SEQ0, unsigned* SEQ1, unsigned* SEQ3,
    int jt0, float (*red)[2][2][256], u16* ldsout)
{
  const int tid=threadIdx.x, w=tid>>6, ln=tid&63, rr=ln&15, kg=ln>>4;
  bf16x8 wreg[2][9];
  #pragma unroll
  for (int u=0;u<2;u++)
    #pragma unroll
    for (int ci=0;ci<9;ci++)
      wreg[u][ci] = *(const bf16x8*)(pW + (((size_t)(jt0+u)*KC0 + (w*9+ci))*64 + ln)*8);

  const int h_=tid>>8, pos=tid&255, l_=pos>>2, i_=pos&3, col_=l_&15, row_=((l_>>4)<<2)+i_, b_=(h_<<4)+row_;
  const float bv0=bias[(jt0<<4)+col_], bv1=bias[((jt0+1)<<4)+col_];
  const int ko0=col_, ko1=16+col_;
  const int faw0=((h_*64)+((b_&15)|((ko0>>3)<<4)))*8+(ko0&7);
  const int faw1=((h_*64)+((b_&15)|((ko1>>3)<<4)))*8+(ko1&7);
  const int myc=jt0>>1, gidx=jt0>>1;

  for (int t=0;t<512;t++){
    if (tid<64){
      poll4(tid, SEQ0,(unsigned)t, (t>=NSLOT)?SEQ1:nullptr,(unsigned)(t-7),
            (t>=NSLOT)?SEQ3:nullptr,(unsigned)(t-7),8, nullptr,0u);
      if (tid==0) acq_inv();
    }
    __syncthreads();
    const int cur=t&7, prv=(t+7)&7;
    const float* xf = input + (size_t)t*4096;
    const u16* h0prv = H0 + (size_t)prv*S0;
    f32x4 acc00={0,0,0,0},acc01={0,0,0,0},acc10={0,0,0,0},acc11={0,0,0,0};
    #pragma unroll
    for (int ci=0;ci<9;ci++){
      bf16x8 a0, a1;
      if (w==0 && ci<4){
        const float* q0 = xf + rr*128 + ci*32 + kg*8;
        const float* q1 = q0 + 16*128;
        f32x4 xa=*(const f32x4*)q0, xb=*(const f32x4*)(q0+4);
        f32x4 ya=*(const f32x4*)q1, yb=*(const f32x4*)(q1+4);
        #pragma unroll
        for (int e=0;e<4;e++){ a0[e]=(__bf16)xa[e]; a0[e+4]=(__bf16)xb[e];
                               a1[e]=(__bf16)ya[e]; a1[e+4]=(__bf16)yb[e]; }
      } else {
        const u16* ap = h0prv + (size_t)(w*9+ci-4)*CH;
        a0 = *(const bf16x8*)(ap + ln*8);
        a1 = *(const bf16x8*)(ap + 512 + ln*8);
      }
      acc00 = MFMA16(a0, wreg[0][ci], acc00);
      acc01 = MFMA16(a1, wreg[0][ci], acc01);
      acc10 = MFMA16(a0, wreg[1][ci], acc10);
      acc11 = MFMA16(a1, wreg[1][ci], acc11);
    }
    #pragma unroll
    for (int i=0;i<4;i++){
      red[w][0][0][(ln<<2)+i]=acc00[i]; red[w][0][1][(ln<<2)+i]=acc01[i];
      red[w][1][0][(ln<<2)+i]=acc10[i]; red[w][1][1][(ln<<2)+i]=acc11[i];
    }
    __syncthreads();
    {
      const u16* hprvc = h0prv + (size_t)myc*CH;
      float v0=0.f, v1=0.f;
      #pragma unroll
      for (int ww=0;ww<8;ww++){ v0 += red[ww][0][h_][pos]; v1 += red[ww][1][h_][pos]; }
      float hp0 = b2f(hprvc[faw0]);
      float hp1 = b2f(hprvc[faw1]);
      ldsout[faw0] = f2b(0.05f*hp0 + 0.95f*tanhf(v0 + bv0));
      ldsout[faw1] = f2b(0.05f*hp1 + 0.95f*tanhf(v1 + bv1));
    }
    __syncthreads();
    if (tid<128){
      f32x4 vv = *(const f32x4*)(ldsout + tid*8);
      st_b128_sc(H0 + (size_t)cur*S0 + (size_t)myc*CH + tid*8, vv);
    }
    drain();
    __syncthreads();
    if (tid==0){ rel_wb(); st_b32_sc(SEQ0+gidx, (unsigned)(t+1)); }
  }
}

// ---------------- projection persistent loop + final-h epilogue ----------------
static __device__ __forceinline__ void run_proj(
    const u16* __restrict__ pW, const float* __restrict__ bo,
    const u16* __restrict__ H0, const u16* __restrict__ H1, const u16* __restrict__ H2,
    float* __restrict__ out, const int* __restrict__ washp,
    unsigned* SEQ0, unsigned* SEQ1, unsigned* SEQ2, unsigned* SEQ3,
    int jt, float (*red)[2][2][256])
{
  const int tid=threadIdx.x, w=tid>>6, ln=tid&63;
  bf16x8 wreg[24];
  #pragma unroll
  for (int ci=0;ci<24;ci++)
    wreg[ci] = *(const bf16x8*)(pW + (((size_t)jt*KCP + (w*24+ci))*64 + ln)*8);
  const int wash = *washp;
  const int h_=tid>>8, pos=tid&255, l_=pos>>2, i_=pos&3, col_=l_&15, row_=((l_>>4)<<2)+i_, b_=(h_<<4)+row_;
  const float bvp = bo[(jt<<4)+col_];

  for (int t=0;t<512;t++){
    if (tid<64){
      poll4(tid, SEQ0,(unsigned)(t+1), SEQ1,(unsigned)(t+1), SEQ2,(unsigned)(t+1),64, nullptr,0u);
      if (tid==0) acq_inv();
    }
    __syncthreads();
    const int cur=t&7;
    const u16* h0c = H0 + (size_t)cur*S0;
    const u16* h1c = H1 + (size_t)cur*S12;
    const u16* h2c = H2 + (size_t)cur*S12;
    f32x4 acc0={0,0,0,0}, acc1={0,0,0,0};
    #pragma unroll
    for (int ci=0;ci<24;ci++){
      const int kc = w*24+ci;
      const u16* ap = (kc<64) ? h0c + (size_t)kc*CH
                    : (kc<128) ? h1c + (size_t)(kc-64)*CH
                               : h2c + (size_t)(kc-128)*CH;
      bf16x8 a0 = *(const bf16x8*)(ap + ln*8);
      bf16x8 a1 = *(const bf16x8*)(ap + 512 + ln*8);
      acc0 = MFMA16(a0, wreg[ci], acc0);
      acc1 = MFMA16(a1, wreg[ci], acc1);
    }
    #pragma unroll
    for (int i=0;i<4;i++){ red[w][0][0][(ln<<2)+i]=acc0[i]; red[w][0][1][(ln<<2)+i]=acc1[i]; }
    __syncthreads();
    if (tid==0) st_b32_sc(SEQ3+jt, (unsigned)(t+1));   // reads of slot done
    if (t >= wash){
      float v=0.f;
      #pragma unroll
      for (int ww=0;ww<8;ww++) v += red[ww][0][h_][pos];
      out[(((size_t)(t-wash))*32 + b_)*128 + (jt<<4)+col_] = v + bvp;
    }
    __syncthreads();
  }
  // final hidden state: slot 7, frag layout -> [layer][b][j] fp32
  for (int q = jt*512 + tid; q < 196608; q += 4096){
    int l = q>>16, rem = q&65535, b = rem>>11, j = rem&2047;
    const u16* h = (l==0)? H0+(size_t)7*S0 : ((l==1)? H1+(size_t)7*S12 : H2+(size_t)7*S12);
    out[1966080 + q] = b2f(h[frag_addr(b,j)]);
  }
}

// ---------------- top-level persistent kernel ----------------
__global__ __launch_bounds__(512) void k_esn(
    const u16* __restrict__ p0, const u16* __restrict__ p1, const u16* __restrict__ p2, const u16* __restrict__ po,
    const float* __restrict__ b0, const float* __restrict__ b1, const float* __restrict__ b2, const float* __restrict__ bo,
    const float* __restrict__ input, const int* __restrict__ washp,
    u16* H0, u16* H1, u16* H2, unsigned* flags, float* out)
{
  __shared__ float red[8][2][2][256];
  __shared__ u16 ldsout[1024];
  const int bid = blockIdx.x;
  unsigned* SEQ0 = flags; unsigned* SEQ1 = flags+64; unsigned* SEQ2 = flags+128; unsigned* SEQ3 = flags+192;

  if (bid < 64)       run_l0 (p0, b0, input, H0, SEQ0, SEQ1, SEQ3, bid*2, red, ldsout);
  else if (bid < 128) run_l12(p1, b1, H0, S0,  H1, SEQ0, SEQ1, SEQ2, 64, SEQ3, (bid-64)*2, red, ldsout);
  else if (bid < 192) run_l12(p2, b2, H1, S12, H2, SEQ1, SEQ2, SEQ3, 8, nullptr, (bid-128)*2, red, ldsout);
  else                run_proj(po, bo, H0, H1, H2, out, washp, SEQ0, SEQ1, SEQ2, SEQ3, bid-192, red);
}

extern "C" void kernel_launch(void* const* d_in, const int* in_sizes, int n_in,
                              void* d_out, int out_size, void* d_ws, size_t ws_size,
                              hipStream_t stream)
{
  (void)in_sizes; (void)n_in; (void)out_size; (void)ws_size;
  const float* input=(const float*)d_in[0];
  const float* wih0=(const float*)d_in[1]; const float* bih0=(const float*)d_in[2];
  const float* whh0=(const float*)d_in[3];
  const float* wih1=(const float*)d_in[4]; const float* bih1=(const float*)d_in[5];
  const float* whh1=(const float*)d_in[6];
  const float* wih2=(const float*)d_in[7]; const float* bih2=(const float*)d_in[8];
  const float* whh2=(const float*)d_in[9];
  const float* wout=(const float*)d_in[10]; const float* bout=(const float*)d_in[11];
  const int* washp=(const int*)d_in[12];
  float* out=(float*)d_out;

  u16* p0=(u16*)d_ws;
  u16* p1=p0+E0P;
  u16* p2=p1+E1P;
  u16* po=p2+E1P;
  u16* H0=po+EPP;
  u16* H1=H0+(size_t)NSLOT*S0;
  u16* H2=H1+(size_t)NSLOT*S12;
  unsigned* flags=(unsigned*)(H2+(size_t)NSLOT*S12);
  size_t totbytes = ((char*)(flags+256)) - ((char*)d_ws);

  hipMemsetAsync(d_ws, 0, totbytes, stream);
  k_pack<<<dim3(2048),dim3(256),0,stream>>>(wih0,whh0,wih1,whh1,wih2,whh2,wout,p0,p1,p2,po);

  void* args[] = { (void*)&p0, (void*)&p1, (void*)&p2, (void*)&po,
                   (void*)&bih0, (void*)&bih1, (void*)&bih2, (void*)&bout,
                   (void*)&input, (void*)&washp,
                   (void*)&H0, (void*)&H1, (void*)&H2, (void*)&flags, (void*)&out };
  hipLaunchCooperativeKernel((const void*)k_esn, dim3(200), dim3(512), args, 0, stream);
}